// Round 8
// baseline (518.104 us; speedup 1.0000x reference)
//
#include <hip/hip_runtime.h>
#include <hip/hip_bf16.h>

#define Bc 512
#define Lc 512
#define Tc 128
#define GBW 16      // batches per wave (= per block)
#define PSTR 136    // padded LDS row stride (elems): 272B rows, 16B-aligned

typedef __attribute__((ext_vector_type(8))) short bf16x8;
typedef __attribute__((ext_vector_type(4))) float f32x4;

__device__ __forceinline__ unsigned short f2bf_u(float f) {
  __hip_bfloat16 h = __float2bfloat16(f);
  unsigned short us;
  __builtin_memcpy(&us, &h, 2);
  return us;
}
__device__ __forceinline__ short f2bf(float f) { return (short)f2bf_u(f); }
__device__ __forceinline__ unsigned pk2(float a, float b) {
  return (unsigned)f2bf_u(a) | ((unsigned)f2bf_u(b) << 16);
}

__global__ __launch_bounds__(64, 1) __attribute__((amdgpu_waves_per_eu(1, 1)))
void crf_forward(const float* __restrict__ x,      // [B,L,T]
                 const float* __restrict__ trans,  // [T,T]
                 const float* __restrict__ startT, // [T]
                 const float* __restrict__ endT,   // [T]
                 const int*   __restrict__ labels, // [B,L]
                 const int*   __restrict__ mask,   // [B,L]
                 float* __restrict__ diff_out,     // [B]
                 float* __restrict__ msum_out)     // [B]
{
  // all LDS is wave-private (1 wave/block): no barriers anywhere
  __shared__ __align__(16) unsigned short tile[GBW * PSTR]; // Abar bf16 [b][j]
  __shared__ unsigned char mTl[Lc * GBW];                   // mask bytes [t][b]
  __shared__ float score_s[GBW];
  __shared__ float msum_s[GBW];

  const int lane = threadIdx.x;   // 0..63, single wave
  const int b16  = lane & 15;
  const int hi   = lane >> 4;     // 0..3
  const int bg0  = blockIdx.x * GBW;

  // ---- stage transposed mask bytes (one-time) ----
  for (int i = lane; i < GBW * Lc; i += 64) {
    int bb = i & 15, t = i >> 4;
    mTl[t * GBW + bb] = (unsigned char)mask[(size_t)(bg0 + bb) * Lc + t];
  }

  // ---- gold-path score + msum (wave-parallel over t, per batch) ----
  for (int bb = 0; bb < GBW; ++bb) {
    const int bglob = bg0 + bb;
    const int* lbp = labels + (size_t)bglob * Lc;
    const int* mkp = mask + (size_t)bglob * Lc;
    const float* xrow = x + (size_t)bglob * Lc * Tc;
    float sp = 0.f, msp = 0.f;
    for (int t = lane; t < Lc; t += 64) {
      int l0 = lbp[t];
      int m0 = mkp[t];
      msp += (float)m0;
      if (t < Lc - 1) {
        int l1 = lbp[t + 1];
        float m1 = (float)mkp[t + 1];
        sp += trans[l0 * Tc + l1] * m1 + xrow[(size_t)t * Tc + l0] * (float)m0;
      }
    }
#pragma unroll
    for (int off = 32; off; off >>= 1) {
      sp += __shfl_xor(sp, off);
      msp += __shfl_xor(msp, off);
    }
    if (lane == 0) {
      int last_idx = (int)msp - 1;
      int lt = lbp[last_idx];
      score_s[bb] = sp + startT[lbp[0]] + endT[lt]
                  + xrow[(size_t)(Lc - 1) * Tc + lt] * (float)mkp[Lc - 1];
      msum_s[bb] = msp;
    }
  }

  // ---- E^T fragments (A-operand, CONSTANT): 32 frags = 128 VGPRs ----
  // A[row][k] for tile JT, chunk Q: lane holds row = b16 (global j' = 16*JT+b16),
  // k = 32Q + 8*hi + e  -> value E[i=k][j'] = exp(trans[i*128 + j'])
#define LOADET(JT, Q) bf16x8 et##JT##_##Q; { \
    _Pragma("unroll") for (int e = 0; e < 8; ++e) \
      et##JT##_##Q[e] = f2bf(__expf(trans[(32*(Q) + 8*hi + e) * Tc + 16*(JT) + b16])); }
  LOADET(0,0) LOADET(0,1) LOADET(0,2) LOADET(0,3)
  LOADET(1,0) LOADET(1,1) LOADET(1,2) LOADET(1,3)
  LOADET(2,0) LOADET(2,1) LOADET(2,2) LOADET(2,3)
  LOADET(3,0) LOADET(3,1) LOADET(3,2) LOADET(3,3)
  LOADET(4,0) LOADET(4,1) LOADET(4,2) LOADET(4,3)
  LOADET(5,0) LOADET(5,1) LOADET(5,2) LOADET(5,3)
  LOADET(6,0) LOADET(6,1) LOADET(6,2) LOADET(6,3)
  LOADET(7,0) LOADET(7,1) LOADET(7,2) LOADET(7,3)
#undef LOADET

  // ---- per-lane bases ----
  // lane owns batch b16, j' slots {16*JT + 4*hi + r} (C layout row=4hi+r, col=b16)
  const float* xlane = x + (size_t)(bg0 + b16) * (Lc * Tc) + 4 * hi;
  unsigned* wb32 = (unsigned*)&tile[(size_t)b16 * PSTR + 4 * hi];
  const unsigned short* rb = &tile[(size_t)b16 * PSTR + 8 * hi];

  bf16x8 Bf0, Bf1, Bf2, Bf3;
  f32x4 ao0, ao1, ao2, ao3, ao4, ao5, ao6, ao7;
  float cacc;

  // ---- init: alpha_0 = start + x_0, renorm by per-batch row max ----
  {
#define INITA(JT) f32x4 a##JT; { \
      f32x4 st_ = *(const f32x4*)&startT[16*(JT) + 4*hi]; \
      f32x4 x0_ = *(const f32x4*)(xlane + 16*(JT)); \
      a##JT = st_ + x0_; }
    INITA(0) INITA(1) INITA(2) INITA(3) INITA(4) INITA(5) INITA(6) INITA(7)
#undef INITA
    float m_ = -1e30f;
#define RMAX(JT) m_ = fmaxf(m_, fmaxf(fmaxf(a##JT.x, a##JT.y), fmaxf(a##JT.z, a##JT.w)));
    RMAX(0) RMAX(1) RMAX(2) RMAX(3) RMAX(4) RMAX(5) RMAX(6) RMAX(7)
#undef RMAX
    m_ = fmaxf(m_, __shfl_xor(m_, 16));
    m_ = fmaxf(m_, __shfl_xor(m_, 32));
    cacc = m_;
#define EXPA(JT) { ao##JT.x = __expf(a##JT.x - m_); ao##JT.y = __expf(a##JT.y - m_); \
                   ao##JT.z = __expf(a##JT.z - m_); ao##JT.w = __expf(a##JT.w - m_); }
    EXPA(0) EXPA(1) EXPA(2) EXPA(3) EXPA(4) EXPA(5) EXPA(6) EXPA(7)
#undef EXPA
  }

#define PACKW(JT) { wb32[8*(JT)] = pk2(ao##JT.x, ao##JT.y); \
                    wb32[8*(JT)+1] = pk2(ao##JT.z, ao##JT.w); }
#define READBF() { Bf0 = *(const bf16x8*)(rb); Bf1 = *(const bf16x8*)(rb + 32); \
                   Bf2 = *(const bf16x8*)(rb + 64); Bf3 = *(const bf16x8*)(rb + 96); }
  PACKW(0) PACKW(1) PACKW(2) PACKW(3) PACKW(4) PACKW(5) PACKW(6) PACKW(7)
  READBF()

  // ---- x prefetch, 2 steps deep ----
  f32x4 xa0, xa1, xa2, xa3, xa4, xa5, xa6, xa7;
  f32x4 xb0, xb1, xb2, xb3, xb4, xb5, xb6, xb7;
#define LOADX8(P, T) { const float* xt0_ = xlane + (size_t)(T) * Tc; \
    P##0 = *(const f32x4*)(xt0_ +   0); P##1 = *(const f32x4*)(xt0_ +  16); \
    P##2 = *(const f32x4*)(xt0_ +  32); P##3 = *(const f32x4*)(xt0_ +  48); \
    P##4 = *(const f32x4*)(xt0_ +  64); P##5 = *(const f32x4*)(xt0_ +  80); \
    P##6 = *(const f32x4*)(xt0_ +  96); P##7 = *(const f32x4*)(xt0_ + 112); }
  LOADX8(xa, 1)
  LOADX8(xb, 2)

  // ---- main recurrence: no barriers, wave-private LDS round trip ----
#define MFMA4(JT) f32x4 cj##JT = {0.f, 0.f, 0.f, 0.f}; \
  cj##JT = __builtin_amdgcn_mfma_f32_16x16x32_bf16(et##JT##_0, Bf0, cj##JT, 0, 0, 0); \
  cj##JT = __builtin_amdgcn_mfma_f32_16x16x32_bf16(et##JT##_1, Bf1, cj##JT, 0, 0, 0); \
  cj##JT = __builtin_amdgcn_mfma_f32_16x16x32_bf16(et##JT##_2, Bf2, cj##JT, 0, 0, 0); \
  cj##JT = __builtin_amdgcn_mfma_f32_16x16x32_bf16(et##JT##_3, Bf3, cj##JT, 0, 0, 0);

#define BLEND1(JT, P) { \
    f32x4 ex_; \
    ex_.x = __expf(P##JT.x); ex_.y = __expf(P##JT.y); \
    ex_.z = __expf(P##JT.z); ex_.w = __expf(P##JT.w); \
    P##JT = *(const f32x4*)(xt_ + 16*(JT)); \
    f32x4 v_ = cj##JT * ex_; \
    ao##JT.x = mvb ? v_.x : ao##JT.x; \
    ao##JT.y = mvb ? v_.y : ao##JT.y; \
    ao##JT.z = mvb ? v_.z : ao##JT.z; \
    ao##JT.w = mvb ? v_.w : ao##JT.w; }

#define STEP(T, P) { \
    const bool mvb = mTl[(T) * GBW + b16] != 0; \
    MFMA4(0) MFMA4(1) MFMA4(2) MFMA4(3) MFMA4(4) MFMA4(5) MFMA4(6) MFMA4(7) \
    int tp_ = (T) + 2; if (tp_ > Lc - 1) tp_ = Lc - 1; \
    const float* xt_ = xlane + (size_t)tp_ * Tc; \
    BLEND1(0, P) BLEND1(1, P) BLEND1(2, P) BLEND1(3, P) \
    BLEND1(4, P) BLEND1(5, P) BLEND1(6, P) BLEND1(7, P) \
    if (((T) & 7) == 0) { \
      float Mf = fmaxf(fmaxf(ao0.x, ao0.y), fmaxf(ao0.z, ao0.w)); \
      Mf = fmaxf(Mf, fmaxf(fmaxf(ao1.x, ao1.y), fmaxf(ao1.z, ao1.w))); \
      Mf = fmaxf(Mf, fmaxf(fmaxf(ao2.x, ao2.y), fmaxf(ao2.z, ao2.w))); \
      Mf = fmaxf(Mf, fmaxf(fmaxf(ao3.x, ao3.y), fmaxf(ao3.z, ao3.w))); \
      Mf = fmaxf(Mf, fmaxf(fmaxf(ao4.x, ao4.y), fmaxf(ao4.z, ao4.w))); \
      Mf = fmaxf(Mf, fmaxf(fmaxf(ao5.x, ao5.y), fmaxf(ao5.z, ao5.w))); \
      Mf = fmaxf(Mf, fmaxf(fmaxf(ao6.x, ao6.y), fmaxf(ao6.z, ao6.w))); \
      Mf = fmaxf(Mf, fmaxf(fmaxf(ao7.x, ao7.y), fmaxf(ao7.z, ao7.w))); \
      Mf = fmaxf(Mf, __shfl_xor(Mf, 16)); \
      Mf = fmaxf(Mf, __shfl_xor(Mf, 32)); \
      int E_ = (int)((__float_as_uint(Mf) >> 23) & 0xffu); \
      float r_ = __uint_as_float((unsigned)(254 - E_) << 23); \
      cacc += (float)(E_ - 127) * 0.6931471805599453f; \
      ao0 *= r_; ao1 *= r_; ao2 *= r_; ao3 *= r_; \
      ao4 *= r_; ao5 *= r_; ao6 *= r_; ao7 *= r_; \
    } \
    PACKW(0) PACKW(1) PACKW(2) PACKW(3) PACKW(4) PACKW(5) PACKW(6) PACKW(7) \
    READBF() \
  }

  for (int t = 1; t < Lc - 1; t += 2) {
    STEP(t, xa)
    STEP(t + 1, xb)
  }
  STEP(Lc - 1, xa)
#undef STEP
#undef BLEND1
#undef MFMA4
#undef PACKW
#undef READBF
#undef LOADX8

  // ---- logZ_b = cacc + log(sum_j' Abar[b][j'] * exp(end[j'])) ----
  float tot = 0.f;
#define FDOT(JT) { f32x4 ev = *(const f32x4*)&endT[16*(JT) + 4*hi]; \
    tot += ao##JT.x * __expf(ev.x) + ao##JT.y * __expf(ev.y) \
         + ao##JT.z * __expf(ev.z) + ao##JT.w * __expf(ev.w); }
  FDOT(0) FDOT(1) FDOT(2) FDOT(3) FDOT(4) FDOT(5) FDOT(6) FDOT(7)
#undef FDOT
  tot += __shfl_xor(tot, 16);
  tot += __shfl_xor(tot, 32);
  if (lane < 16) {
    float logZ = cacc + __logf(tot);
    diff_out[bg0 + b16] = logZ - score_s[b16];
    msum_out[bg0 + b16] = msum_s[b16];
  }
}

__global__ __launch_bounds__(512)
void crf_final(const float* __restrict__ diff, const float* __restrict__ msum,
               float* __restrict__ out)
{
  __shared__ float sd[512];
  __shared__ float sm[512];
  int t = threadIdx.x;
  sd[t] = diff[t];
  sm[t] = msum[t];
  __syncthreads();
  for (int s = 256; s > 0; s >>= 1) {
    if (t < s) { sd[t] += sd[t + s]; sm[t] += sm[t + s]; }
    __syncthreads();
  }
  if (t == 0) out[0] = sd[0] / sm[0];
}

extern "C" void kernel_launch(void* const* d_in, const int* in_sizes, int n_in,
                              void* d_out, int out_size, void* d_ws, size_t ws_size,
                              hipStream_t stream) {
  const float* x      = (const float*)d_in[0];
  const float* trans  = (const float*)d_in[1];
  const float* startT = (const float*)d_in[2];
  const float* endT   = (const float*)d_in[3];
  const int*   labels = (const int*)d_in[4];
  const int*   mask   = (const int*)d_in[5];
  float* out = (float*)d_out;
  float* ws  = (float*)d_ws;
  float* diff = ws;        // [512]
  float* msum = ws + Bc;   // [512]

  crf_forward<<<dim3(Bc / GBW), dim3(64), 0, stream>>>(
      x, trans, startT, endT, labels, mask, diff, msum);
  crf_final<<<dim3(1), dim3(512), 0, stream>>>(diff, msum, out);
}

// Round 9
// 381.975 us; speedup vs baseline: 1.3564x; 1.3564x over previous
//
#include <hip/hip_runtime.h>
#include <hip/hip_bf16.h>

#define Bc 512
#define Lc 512
#define Tc 128
#define GB 16     // batches per block
#define PSTR 136  // padded tile row stride (u16 elems): 272B rows
#define PBUF (GB * PSTR)

typedef __attribute__((ext_vector_type(8))) short bf16x8;
typedef __attribute__((ext_vector_type(4))) float f32x4;
typedef __attribute__((ext_vector_type(2))) float f32x2;

// raw barrier: drain LDS ops only; global prefetches stay in flight
__device__ __forceinline__ void bar_lgkm() {
  asm volatile("s_waitcnt lgkmcnt(0)\n\ts_barrier" ::: "memory");
}

__device__ __forceinline__ unsigned short f2bf_u(float f) {
  __hip_bfloat16 h = __float2bfloat16(f);
  unsigned short us;
  __builtin_memcpy(&us, &h, 2);
  return us;
}
__device__ __forceinline__ short f2bf(float f) { return (short)f2bf_u(f); }
__device__ __forceinline__ unsigned pk2(float a, float b) {
  return (unsigned)f2bf_u(a) | ((unsigned)f2bf_u(b) << 16);
}

__global__ __launch_bounds__(128, 1) __attribute__((amdgpu_waves_per_eu(1, 1)))
void crf_forward(const float* __restrict__ x,      // [B,L,T]
                 const float* __restrict__ trans,  // [T,T]
                 const float* __restrict__ startT, // [T]
                 const float* __restrict__ endT,   // [T]
                 const int*   __restrict__ labels, // [B,L]
                 const int*   __restrict__ mask,   // [B,L]
                 float* __restrict__ diff_out,     // [B]
                 float* __restrict__ msum_out)     // [B]
{
  __shared__ __align__(16) unsigned short Pl[2 * PBUF]; // double-buffered Abar bf16 [b][j']
  __shared__ __align__(16) float r_s[2][GB];            // double-buffered rescale bcast
  __shared__ __align__(16) unsigned char mT[Lc][GB];    // transposed mask bytes [t][b]
  __shared__ __align__(16) float c_s[GB];
  __shared__ float score_s[GB];
  __shared__ float msum_s[GB];
  __shared__ float red[2][GB];

  const int tid  = threadIdx.x;     // 0..127 (2 waves)
  const int lane = tid & 63;
  const int w    = tid >> 6;        // wave 0/1: owns j'-cols [64w, 64w+64)
  const int crow = lane & 15;
  const int khi  = lane >> 4;       // 0..3
  const int bg0  = blockIdx.x * GB;

  // ---- stage transposed mask bytes ----
  for (int i = tid; i < GB * Lc; i += 128) {
    int bb = i >> 9, t = i & (Lc - 1);
    mT[t][bb] = (unsigned char)mask[(size_t)(bg0 + bb) * Lc + t];
  }

  // ---- gold-path score + msum: wave w handles local batches 8w..8w+7 ----
  for (int bb = 8 * w; bb < 8 * w + 8; ++bb) {
    const int bglob = bg0 + bb;
    const int* lbp = labels + (size_t)bglob * Lc;
    const int* mkp = mask + (size_t)bglob * Lc;
    const float* xrow = x + (size_t)bglob * Lc * Tc;
    float sp = 0.f, msp = 0.f;
    for (int t = lane; t < Lc; t += 64) {
      int l0 = lbp[t];
      int m0 = mkp[t];
      msp += (float)m0;
      if (t < Lc - 1) {
        int l1 = lbp[t + 1];
        float m1 = (float)mkp[t + 1];
        sp += trans[l0 * Tc + l1] * m1 + xrow[(size_t)t * Tc + l0] * (float)m0;
      }
    }
#pragma unroll
    for (int off = 32; off; off >>= 1) {
      sp += __shfl_xor(sp, off);
      msp += __shfl_xor(msp, off);
    }
    if (lane == 0) {
      int last_idx = (int)msp - 1;
      int lt = lbp[last_idx];
      score_s[bb] = sp + startT[lbp[0]] + endT[lt]
                  + xrow[(size_t)(Lc - 1) * Lc * 0 + (size_t)(Lc - 1) * Tc + lt] * (float)mkp[Lc - 1];
      msum_s[bb] = msp;
    }
  }

  // ---- E-frags (B-operand): wave's 64 cols as col-pairs (2crow, 2crow+1) ----
  // U in {0,1}: col base 64w + 32U + 2crow; Q = k-chunk. 16 frags = 64 VGPRs.
  const int colA = 64 * w + 2 * crow;
#define LOADE(U, Q, DA, DB) bf16x8 DA, DB; { \
    _Pragma("unroll") for (int e = 0; e < 8; ++e) { \
      const float* tp__ = trans + (32 * (Q) + 8 * khi + e) * Tc + colA + 32 * (U); \
      DA[e] = f2bf(__expf(tp__[0])); \
      DB[e] = f2bf(__expf(tp__[1])); } }
  LOADE(0, 0, eA00, eB00) LOADE(0, 1, eA01, eB01)
  LOADE(0, 2, eA02, eB02) LOADE(0, 3, eA03, eB03)
  LOADE(1, 0, eA10, eB10) LOADE(1, 1, eA11, eB11)
  LOADE(1, 2, eA12, eB12) LOADE(1, 3, eA13, eB13)
#undef LOADE

  // ---- per-lane constant offsets (elem units) ----
  const int aoff  = (lane & 15) * PSTR + 8 * khi;   // A-frag: row=batch(lane&15), k=8khi
  const int wbase = (4 * khi) * PSTR + colA;        // C write: rows 4khi+r, col pair
  const float* xp0 = x + (size_t)(bg0 + 4 * khi + 0) * Lc * Tc + colA;
  const float* xp1 = x + (size_t)(bg0 + 4 * khi + 1) * Lc * Tc + colA;
  const float* xp2 = x + (size_t)(bg0 + 4 * khi + 2) * Lc * Tc + colA;
  const float* xp3 = x + (size_t)(bg0 + 4 * khi + 3) * Lc * Tc + colA;
  const bool rlane = (w == 0) && (crow == 0);       // 4 lanes own rescale/c (col j'=0)

  __syncthreads();  // mT staged

  // ---- init: alpha_0 = start + x_0; exact renorm by alpha_0[b][0] ----
  f32x2 s0 = *(const f32x2*)&startT[colA];
  f32x2 s1 = *(const f32x2*)&startT[colA + 32];
  f32x2 i00 = s0 + *(const f32x2*)xp0;
  f32x2 i01 = s0 + *(const f32x2*)xp1;
  f32x2 i02 = s0 + *(const f32x2*)xp2;
  f32x2 i03 = s0 + *(const f32x2*)xp3;
  f32x2 i10 = s1 + *(const f32x2*)(xp0 + 32);
  f32x2 i11 = s1 + *(const f32x2*)(xp1 + 32);
  f32x2 i12 = s1 + *(const f32x2*)(xp2 + 32);
  f32x2 i13 = s1 + *(const f32x2*)(xp3 + 32);
  f32x4 aA0 = {i00.x, i01.x, i02.x, i03.x};   // even col of U0, batches 4khi+0..3
  f32x4 aB0 = {i00.y, i01.y, i02.y, i03.y};
  f32x4 aA1 = {i10.x, i11.x, i12.x, i13.x};
  f32x4 aB1 = {i10.y, i11.y, i12.y, i13.y};
  if (rlane) *(f32x4*)&r_s[1][khi << 2] = aA0;  // rlane's even-U0 col IS j'=0
  __syncthreads();
  f32x4 cb = *(const f32x4*)&r_s[1][khi << 2];
  f32x4 AoA0, AoB0, AoA1, AoB1;
  AoA0.x = __expf(aA0.x - cb.x); AoA0.y = __expf(aA0.y - cb.y);
  AoA0.z = __expf(aA0.z - cb.z); AoA0.w = __expf(aA0.w - cb.w);
  AoB0.x = __expf(aB0.x - cb.x); AoB0.y = __expf(aB0.y - cb.y);
  AoB0.z = __expf(aB0.z - cb.z); AoB0.w = __expf(aB0.w - cb.w);
  AoA1.x = __expf(aA1.x - cb.x); AoA1.y = __expf(aA1.y - cb.y);
  AoA1.z = __expf(aA1.z - cb.z); AoA1.w = __expf(aA1.w - cb.w);
  AoB1.x = __expf(aB1.x - cb.x); AoB1.y = __expf(aB1.y - cb.y);
  AoB1.z = __expf(aB1.z - cb.z); AoB1.w = __expf(aB1.w - cb.w);
  *(unsigned*)&Pl[PBUF + wbase + 0 * PSTR +  0] = pk2(AoA0.x, AoB0.x);
  *(unsigned*)&Pl[PBUF + wbase + 0 * PSTR + 32] = pk2(AoA1.x, AoB1.x);
  *(unsigned*)&Pl[PBUF + wbase + 1 * PSTR +  0] = pk2(AoA0.y, AoB0.y);
  *(unsigned*)&Pl[PBUF + wbase + 1 * PSTR + 32] = pk2(AoA1.y, AoB1.y);
  *(unsigned*)&Pl[PBUF + wbase + 2 * PSTR +  0] = pk2(AoA0.z, AoB0.z);
  *(unsigned*)&Pl[PBUF + wbase + 2 * PSTR + 32] = pk2(AoA1.z, AoB1.z);
  *(unsigned*)&Pl[PBUF + wbase + 3 * PSTR +  0] = pk2(AoA0.w, AoB0.w);
  *(unsigned*)&Pl[PBUF + wbase + 3 * PSTR + 32] = pk2(AoA1.w, AoB1.w);
  f32x4 c  = rlane ? cb : (f32x4){0.f, 0.f, 0.f, 0.f};
  f32x4 lr = {0.f, 0.f, 0.f, 0.f};
  __syncthreads();                  // cb reads done -> safe to overwrite r_s[1]
  if (rlane) {
    f32x4 one = {1.f, 1.f, 1.f, 1.f};
    *(f32x4*)&r_s[1][khi << 2] = one;
  }
  // depth-1 x prefetch for t=1
  f32x2 X00 = *(const f32x2*)(xp0 + Tc),      X10 = *(const f32x2*)(xp0 + Tc + 32);
  f32x2 X01 = *(const f32x2*)(xp1 + Tc),      X11 = *(const f32x2*)(xp1 + Tc + 32);
  f32x2 X02 = *(const f32x2*)(xp2 + Tc),      X12 = *(const f32x2*)(xp2 + Tc + 32);
  f32x2 X03 = *(const f32x2*)(xp3 + Tc),      X13 = *(const f32x2*)(xp3 + Tc + 32);
  __syncthreads();                  // Pl[1], r_s[1] visible

#define MFMA_(A, B, C_) C_ = __builtin_amdgcn_mfma_f32_16x16x32_bf16(A, B, C_, 0, 0, 0)
#define STEP(T, RB, WB) do {                                                   \
    bf16x8 Af0 = *(const bf16x8*)&Pl[(RB) * PBUF + aoff +  0];                 \
    bf16x8 Af1 = *(const bf16x8*)&Pl[(RB) * PBUF + aoff + 32];                 \
    bf16x8 Af2 = *(const bf16x8*)&Pl[(RB) * PBUF + aoff + 64];                 \
    bf16x8 Af3 = *(const bf16x8*)&Pl[(RB) * PBUF + aoff + 96];                 \
    f32x4 rr = *(const f32x4*)&r_s[RB][khi << 2];                              \
    unsigned mw = *(const unsigned*)&mT[T][khi << 2];                          \
    f32x2 e00 = {__expf(X00.x), __expf(X00.y)};                                \
    f32x2 e01 = {__expf(X01.x), __expf(X01.y)};                                \
    f32x2 e02 = {__expf(X02.x), __expf(X02.y)};                                \
    f32x2 e03 = {__expf(X03.x), __expf(X03.y)};                                \
    f32x2 e10 = {__expf(X10.x), __expf(X10.y)};                                \
    f32x2 e11 = {__expf(X11.x), __expf(X11.y)};                                \
    f32x2 e12 = {__expf(X12.x), __expf(X12.y)};                                \
    f32x2 e13 = {__expf(X13.x), __expf(X13.y)};                                \
    int tn_ = (T) + 1; if (tn_ > Lc - 1) tn_ = Lc - 1;                         \
    size_t xo_ = (size_t)tn_ * Tc;                                             \
    X00 = *(const f32x2*)(xp0 + xo_); X10 = *(const f32x2*)(xp0 + xo_ + 32);   \
    X01 = *(const f32x2*)(xp1 + xo_); X11 = *(const f32x2*)(xp1 + xo_ + 32);   \
    X02 = *(const f32x2*)(xp2 + xo_); X12 = *(const f32x2*)(xp2 + xo_ + 32);   \
    X03 = *(const f32x2*)(xp3 + xo_); X13 = *(const f32x2*)(xp3 + xo_ + 32);   \
    f32x4 CA0 = {0.f,0.f,0.f,0.f}, CB0 = {0.f,0.f,0.f,0.f};                    \
    f32x4 CA1 = {0.f,0.f,0.f,0.f}, CB1 = {0.f,0.f,0.f,0.f};                    \
    MFMA_(Af0, eA00, CA0); MFMA_(Af1, eA01, CA0);                              \
    MFMA_(Af2, eA02, CA0); MFMA_(Af3, eA03, CA0);                              \
    MFMA_(Af0, eB00, CB0); MFMA_(Af1, eB01, CB0);                              \
    MFMA_(Af2, eB02, CB0); MFMA_(Af3, eB03, CB0);                              \
    MFMA_(Af0, eA10, CA1); MFMA_(Af1, eA11, CA1);                              \
    MFMA_(Af2, eA12, CA1); MFMA_(Af3, eA13, CA1);                              \
    MFMA_(Af0, eB10, CB1); MFMA_(Af1, eB11, CB1);                              \
    MFMA_(Af2, eB12, CB1); MFMA_(Af3, eB13, CB1);                              \
    bool m0 = (mw & 0x1u) != 0, m1 = (mw & 0x100u) != 0;                       \
    bool m2 = (mw & 0x10000u) != 0, m3 = (mw & 0x1000000u) != 0;               \
    AoA0.x = m0 ? CA0.x * rr.x * e00.x : AoA0.x;                               \
    AoB0.x = m0 ? CB0.x * rr.x * e00.y : AoB0.x;                               \
    AoA1.x = m0 ? CA1.x * rr.x * e10.x : AoA1.x;                               \
    AoB1.x = m0 ? CB1.x * rr.x * e10.y : AoB1.x;                               \
    AoA0.y = m1 ? CA0.y * rr.y * e01.x : AoA0.y;                               \
    AoB0.y = m1 ? CB0.y * rr.y * e01.y : AoB0.y;                               \
    AoA1.y = m1 ? CA1.y * rr.y * e11.x : AoA1.y;                               \
    AoB1.y = m1 ? CB1.y * rr.y * e11.y : AoB1.y;                               \
    AoA0.z = m2 ? CA0.z * rr.z * e02.x : AoA0.z;                               \
    AoB0.z = m2 ? CB0.z * rr.z * e02.y : AoB0.z;                               \
    AoA1.z = m2 ? CA1.z * rr.z * e12.x : AoA1.z;                               \
    AoB1.z = m2 ? CB1.z * rr.z * e12.y : AoB1.z;                               \
    AoA0.w = m3 ? CA0.w * rr.w * e03.x : AoA0.w;                               \
    AoB0.w = m3 ? CB0.w * rr.w * e03.y : AoB0.w;                               \
    AoA1.w = m3 ? CA1.w * rr.w * e13.x : AoA1.w;                               \
    AoB1.w = m3 ? CB1.w * rr.w * e13.y : AoB1.w;                               \
    *(unsigned*)&Pl[(WB) * PBUF + wbase + 0 * PSTR +  0] = pk2(AoA0.x, AoB0.x);\
    *(unsigned*)&Pl[(WB) * PBUF + wbase + 0 * PSTR + 32] = pk2(AoA1.x, AoB1.x);\
    *(unsigned*)&Pl[(WB) * PBUF + wbase + 1 * PSTR +  0] = pk2(AoA0.y, AoB0.y);\
    *(unsigned*)&Pl[(WB) * PBUF + wbase + 1 * PSTR + 32] = pk2(AoA1.y, AoB1.y);\
    *(unsigned*)&Pl[(WB) * PBUF + wbase + 2 * PSTR +  0] = pk2(AoA0.z, AoB0.z);\
    *(unsigned*)&Pl[(WB) * PBUF + wbase + 2 * PSTR + 32] = pk2(AoA1.z, AoB1.z);\
    *(unsigned*)&Pl[(WB) * PBUF + wbase + 3 * PSTR +  0] = pk2(AoA0.w, AoB0.w);\
    *(unsigned*)&Pl[(WB) * PBUF + wbase + 3 * PSTR + 32] = pk2(AoA1.w, AoB1.w);\
    if (rlane) {                                                               \
      c.x += m0 ? lr.x : 0.f; c.y += m1 ? lr.y : 0.f;                          \
      c.z += m2 ? lr.z : 0.f; c.w += m3 ? lr.w : 0.f;                          \
      int E0 = (int)((__float_as_uint(CA0.x) >> 23) & 0xffu) - 127;            \
      int E1 = (int)((__float_as_uint(CA0.y) >> 23) & 0xffu) - 127;            \
      int E2 = (int)((__float_as_uint(CA0.z) >> 23) & 0xffu) - 127;            \
      int E3 = (int)((__float_as_uint(CA0.w) >> 23) & 0xffu) - 127;            \
      lr.x = (float)E0 * 0.6931471805599453f;                                  \
      lr.y = (float)E1 * 0.6931471805599453f;                                  \
      lr.z = (float)E2 * 0.6931471805599453f;                                  \
      lr.w = (float)E3 * 0.6931471805599453f;                                  \
      f32x4 rv;                                                                \
      rv.x = __uint_as_float((unsigned)(127 - E0) << 23);                      \
      rv.y = __uint_as_float((unsigned)(127 - E1) << 23);                      \
      rv.z = __uint_as_float((unsigned)(127 - E2) << 23);                      \
      rv.w = __uint_as_float((unsigned)(127 - E3) << 23);                      \
      *(f32x4*)&r_s[WB][khi << 2] = rv;                                        \
    }                                                                          \
    bar_lgkm();                                                                \
  } while (0)

  for (int t = 1; t < Lc; t += 2) {
    STEP(t, 1, 0);
    if (t + 1 < Lc) STEP(t + 1, 0, 1);
  }
#undef STEP
#undef MFMA_

  // ---- logZ_b = c_b + log(sum_j' Abar[b][j'] * exp(end[j'])) ----
  if (rlane) *(f32x4*)&c_s[khi << 2] = c;
  f32x2 ed0 = *(const f32x2*)&endT[colA];
  f32x2 ed1 = *(const f32x2*)&endT[colA + 32];
  f32x2 ee0 = {__expf(ed0.x), __expf(ed0.y)};
  f32x2 ee1 = {__expf(ed1.x), __expf(ed1.y)};
  f32x4 sres;
  sres.x = AoA0.x * ee0.x + AoB0.x * ee0.y + AoA1.x * ee1.x + AoB1.x * ee1.y;
  sres.y = AoA0.y * ee0.x + AoB0.y * ee0.y + AoA1.y * ee1.x + AoB1.y * ee1.y;
  sres.z = AoA0.z * ee0.x + AoB0.z * ee0.y + AoA1.z * ee1.x + AoB1.z * ee1.y;
  sres.w = AoA0.w * ee0.x + AoB0.w * ee0.y + AoA1.w * ee1.x + AoB1.w * ee1.y;
#pragma unroll
  for (int off = 1; off < 16; off <<= 1) {
    sres.x += __shfl_xor(sres.x, off);
    sres.y += __shfl_xor(sres.y, off);
    sres.z += __shfl_xor(sres.z, off);
    sres.w += __shfl_xor(sres.w, off);
  }
  if (crow == 0) *(f32x4*)&red[w][khi << 2] = sres;
  __syncthreads();
  if (tid < GB) {
    float tot = red[0][tid] + red[1][tid];
    float logZ = c_s[tid] + __logf(tot);
    diff_out[bg0 + tid] = logZ - score_s[tid];
    msum_out[bg0 + tid] = msum_s[tid];
  }
}

__global__ __launch_bounds__(512)
void crf_final(const float* __restrict__ diff, const float* __restrict__ msum,
               float* __restrict__ out)
{
  __shared__ float sd[512];
  __shared__ float sm[512];
  int t = threadIdx.x;
  sd[t] = diff[t];
  sm[t] = msum[t];
  __syncthreads();
  for (int s = 256; s > 0; s >>= 1) {
    if (t < s) { sd[t] += sd[t + s]; sm[t] += sm[t + s]; }
    __syncthreads();
  }
  if (t == 0) out[0] = sd[0] / sm[0];
}

extern "C" void kernel_launch(void* const* d_in, const int* in_sizes, int n_in,
                              void* d_out, int out_size, void* d_ws, size_t ws_size,
                              hipStream_t stream) {
  const float* x      = (const float*)d_in[0];
  const float* trans  = (const float*)d_in[1];
  const float* startT = (const float*)d_in[2];
  const float* endT   = (const float*)d_in[3];
  const int*   labels = (const int*)d_in[4];
  const int*   mask   = (const int*)d_in[5];
  float* out = (float*)d_out;
  float* ws  = (float*)d_ws;
  float* diff = ws;        // [512]
  float* msum = ws + Bc;   // [512]

  crf_forward<<<dim3(Bc / GB), dim3(128), 0, stream>>>(
      x, trans, startT, endT, labels, mask, diff, msum);
  crf_final<<<dim3(1), dim3(512), 0, stream>>>(diff, msum, out);
}